// Round 1
// baseline (147.555 us; speedup 1.0000x reference)
//
#include <hip/hip_runtime.h>
#include <hip/hip_bf16.h>
#include <cstdint>

// TT-linear: y[4096,4096] = x[4096,1024] @ W[1024,4096] + bias
// Kernel 1 (prep): fused x->bf16 convert + W^T reconstruction from TT cores (unchanged).
// Kernel 2 (tt_gemm): 256x256 tile, 8 waves, BK=32, 4-deep LDS pipeline with
//   counted vmcnt(8) (loads in flight across barriers, T3+T4), XOR-swizzled LDS,
//   s_setprio around MFMA clusters (T5).

typedef __bf16 bf16x8 __attribute__((ext_vector_type(8)));
typedef float f32x4 __attribute__((ext_vector_type(4)));

__device__ __forceinline__ void g2lds16(const void* g, void* l) {
    __builtin_amdgcn_global_load_lds(
        (const __attribute__((address_space(1))) void*)g,
        (__attribute__((address_space(3))) void*)l,
        16, 0, 0);
}

// --------------------------------------------------------------------- prep
__global__ __launch_bounds__(256) void prep(
    const float* __restrict__ x, __bf16* __restrict__ xb,
    const float* __restrict__ c0, const float* __restrict__ c1,
    const float* __restrict__ c2, const float* __restrict__ c3,
    __bf16* __restrict__ wt) {
    const int b = blockIdx.x;
    const int t = threadIdx.x;
    if (b < 2048) {
        const int i = (b * 256 + t) * 8;
        float4 a0 = *(const float4*)(x + i);
        float4 a1 = *(const float4*)(x + i + 4);
        bf16x8 o;
        o[0] = (__bf16)a0.x; o[1] = (__bf16)a0.y; o[2] = (__bf16)a0.z; o[3] = (__bf16)a0.w;
        o[4] = (__bf16)a1.x; o[5] = (__bf16)a1.y; o[6] = (__bf16)a1.z; o[7] = (__bf16)a1.w;
        *(bf16x8*)(xb + i) = o;
        return;
    }
    __shared__ float t12[4][16];     // [wave][r2]
    __shared__ float t123[4][512];   // [wave][m3*8+n3][r3]
    __shared__ float c3s[512];       // [(r3*4+m4)*8+n4]
    #pragma unroll
    for (int i = t; i < 512; i += 256) c3s[i] = c3[i];
    const int s = t >> 6;
    const int lane = t & 63;
    const int g = (b - 2048) * 4 + s;
    const int m1 = g >> 9, n1 = (g >> 6) & 7, m2 = (g >> 3) & 7, n2 = g & 7;
    __syncthreads();
    if (lane < 16) {
        const int r2 = lane;
        float sum = 0.f;
        #pragma unroll
        for (int r1 = 0; r1 < 16; ++r1)
            sum += c0[(m1 * 8 + n1) * 16 + r1] * c1[((r1 * 8 + m2) * 8 + n2) * 16 + r2];
        t12[s][r2] = sum;
    }
    __syncthreads();
    #pragma unroll
    for (int idx = lane; idx < 512; idx += 64) {
        const int m3 = idx >> 7, n3 = (idx >> 4) & 7, r3 = idx & 15;
        float sum = 0.f;
        #pragma unroll
        for (int r2 = 0; r2 < 16; ++r2)
            sum += t12[s][r2] * c2[((r2 * 4 + m3) * 8 + n3) * 16 + r3];
        t123[s][(m3 * 8 + n3) * 16 + r3] = sum;
    }
    __syncthreads();
    const int n3 = lane >> 3, n4 = lane & 7;
    const int n = ((n1 * 8 + n2) * 8 + n3) * 8 + n4;
    const int kbase = (m1 * 8 + m2) * 16;
    float v[16];
    #pragma unroll
    for (int e = 0; e < 16; ++e) v[e] = 0.f;
    #pragma unroll
    for (int m3 = 0; m3 < 4; ++m3) {
        #pragma unroll
        for (int r3 = 0; r3 < 16; ++r3) {
            const float tv = t123[s][(m3 * 8 + n3) * 16 + r3];
            #pragma unroll
            for (int m4 = 0; m4 < 4; ++m4)
                v[m3 * 4 + m4] += tv * c3s[(r3 * 4 + m4) * 8 + n4];
        }
    }
    bf16x8 lo, hi;
    #pragma unroll
    for (int e = 0; e < 8; ++e) { lo[e] = (__bf16)v[e]; hi[e] = (__bf16)v[8 + e]; }
    *(bf16x8*)(wt + (size_t)n * 1024 + kbase)     = lo;
    *(bf16x8*)(wt + (size_t)n * 1024 + kbase + 8) = hi;
}

// -------------------------------------------------------------- GEMM + bias
// C[4096,4096] f32 = A[4096,1024] bf16 @ Bt[4096,1024]^T bf16 + bias
// 256x256 block tile, BK=32, 8 waves (2M x 4N), per-wave 128x64 output.
// LDS: 4 buffers x (A 16KB + B 16KB) = 128 KB. Pipeline: during tile t's two
// phases we stage tile t+3 (A at P1, B at P2). vmcnt(8) at P2 forces everything
// except the newest 8 loads complete => tile t+1 (staged 2 tiles ago) is ready.
// Buffer b[(t+3)&3] = b[(t-1)&3] is only written after tile t-1's end barrier,
// by which point every wave's ds_reads of it have retired (lgkmcnt before MFMA).
// Swizzle: 64-B rows, 4 x 16B chunks; physical chunk pc holds logical pc^((r>>1)&3)
// => fragment ds_read_b128 lands 2 lanes/bank (free). Staging pre-swizzles the
// GLOBAL source; LDS dest stays linear (global_load_lds requirement).

#define BAR() asm volatile("s_barrier" ::: "memory")
#define VMCNT(n) asm volatile("s_waitcnt vmcnt(" #n ")" ::: "memory")

__global__ __launch_bounds__(512, 2) void tt_gemm(
    const __bf16* __restrict__ A, const __bf16* __restrict__ B,
    const float* __restrict__ bias, float* __restrict__ C) {
    constexpr int K = 1024, N = 4096;
    constexpr int NT = K / 32;              // 32 k-tiles
    __shared__ __bf16 sA[4][256 * 32];      // 4 x 16 KB
    __shared__ __bf16 sB[4][256 * 32];      // 4 x 16 KB
    const int t = threadIdx.x;
    const int lane = t & 63;
    const int wave = t >> 6;                // 0..7
    const int wm = (wave >> 2) * 128;       // 0 / 128
    const int wn = (wave & 3) * 64;         // 0..192
    const int l15 = lane & 15, lh = lane >> 4;
    const int coff = (lh ^ ((l15 >> 1) & 3)) * 16;  // swizzled byte offset in 64-B row

    // XCD-aware swizzle: each XCD owns an 8m x 4n rectangle of tiles (bijective)
    const int xcd = blockIdx.x & 7;
    const int lid = blockIdx.x >> 3;        // 0..31
    const int bm = ((xcd >> 2) * 8 + (lid & 7)) * 256;
    const int bn = ((xcd & 3) * 4 + (lid >> 3)) * 256;

    // staging: thread owns chunks c = t and t+512 of each 1024-chunk tile
    const int c0i = t, c1i = t + 512;
    const int r0 = c0i >> 2, r1 = c1i >> 2;             // tile row 0..255
    const int lc0 = (c0i & 3) ^ ((r0 >> 1) & 3);        // logical (global) chunk
    const int lc1 = (c1i & 3) ^ ((r1 >> 1) & 3);
    const __bf16* a0p = A + (size_t)(bm + r0) * K + lc0 * 8;
    const __bf16* a1p = A + (size_t)(bm + r1) * K + lc1 * 8;
    const __bf16* b0p = B + (size_t)(bn + r0) * K + lc0 * 8;
    const __bf16* b1p = B + (size_t)(bn + r1) * K + lc1 * 8;

#define STAGE_A(kt) do { \
    g2lds16(a0p + (kt) * 32, (char*)sA[(kt) & 3] + c0i * 16); \
    g2lds16(a1p + (kt) * 32, (char*)sA[(kt) & 3] + c1i * 16); } while (0)
#define STAGE_B(kt) do { \
    g2lds16(b0p + (kt) * 32, (char*)sB[(kt) & 3] + c0i * 16); \
    g2lds16(b1p + (kt) * 32, (char*)sB[(kt) & 3] + c1i * 16); } while (0)

    f32x4 acc[8][4] = {};

    // prologue: stage tiles 0,1,2 (12 loads); wait until tile 0 (oldest 4) done
    STAGE_A(0); STAGE_B(0);
    STAGE_A(1); STAGE_B(1);
    STAGE_A(2); STAGE_B(2);
    VMCNT(8);
    BAR();

    #pragma unroll 1
    for (int kt = 0; kt < NT - 3; ++kt) {
        const char* la = (const char*)sA[kt & 3];
        const char* lb = (const char*)sB[kt & 3];
        bf16x8 af[4], bfr[4];
        // ---- phase 1: read A rows wm..wm+63 + all B frags; stage A of kt+3
        #pragma unroll
        for (int mi = 0; mi < 4; ++mi)
            af[mi] = *(const bf16x8*)(la + (wm + mi * 16 + l15) * 64 + coff);
        #pragma unroll
        for (int ni = 0; ni < 4; ++ni)
            bfr[ni] = *(const bf16x8*)(lb + (wn + ni * 16 + l15) * 64 + coff);
        STAGE_A(kt + 3);
        BAR();
        __builtin_amdgcn_s_setprio(1);
        #pragma unroll
        for (int mi = 0; mi < 4; ++mi)
            #pragma unroll
            for (int ni = 0; ni < 4; ++ni)
                acc[mi][ni] = __builtin_amdgcn_mfma_f32_16x16x32_bf16(
                    af[mi], bfr[ni], acc[mi][ni], 0, 0, 0);
        __builtin_amdgcn_s_setprio(0);
        BAR();
        // ---- phase 2: read A rows wm+64..wm+127; stage B of kt+3; counted wait
        #pragma unroll
        for (int mi = 0; mi < 4; ++mi)
            af[mi] = *(const bf16x8*)(la + (wm + 64 + mi * 16 + l15) * 64 + coff);
        STAGE_B(kt + 3);
        VMCNT(8);
        BAR();
        __builtin_amdgcn_s_setprio(1);
        #pragma unroll
        for (int mi = 0; mi < 4; ++mi)
            #pragma unroll
            for (int ni = 0; ni < 4; ++ni)
                acc[4 + mi][ni] = __builtin_amdgcn_mfma_f32_16x16x32_bf16(
                    af[mi], bfr[ni], acc[4 + mi][ni], 0, 0, 0);
        __builtin_amdgcn_s_setprio(0);
        BAR();
    }

    // drain remaining stages (tiles 30,31), then 3 tail tiles (no LDS writes left)
    VMCNT(0);
    BAR();
    #pragma unroll
    for (int kt = NT - 3; kt < NT; ++kt) {
        const char* la = (const char*)sA[kt & 3];
        const char* lb = (const char*)sB[kt & 3];
        bf16x8 af[4], bfr[4];
        #pragma unroll
        for (int ni = 0; ni < 4; ++ni)
            bfr[ni] = *(const bf16x8*)(lb + (wn + ni * 16 + l15) * 64 + coff);
        #pragma unroll
        for (int mi = 0; mi < 4; ++mi)
            af[mi] = *(const bf16x8*)(la + (wm + mi * 16 + l15) * 64 + coff);
        #pragma unroll
        for (int mi = 0; mi < 4; ++mi)
            #pragma unroll
            for (int ni = 0; ni < 4; ++ni)
                acc[mi][ni] = __builtin_amdgcn_mfma_f32_16x16x32_bf16(
                    af[mi], bfr[ni], acc[mi][ni], 0, 0, 0);
        #pragma unroll
        for (int mi = 0; mi < 4; ++mi)
            af[mi] = *(const bf16x8*)(la + (wm + 64 + mi * 16 + l15) * 64 + coff);
        #pragma unroll
        for (int mi = 0; mi < 4; ++mi)
            #pragma unroll
            for (int ni = 0; ni < 4; ++ni)
                acc[4 + mi][ni] = __builtin_amdgcn_mfma_f32_16x16x32_bf16(
                    af[mi], bfr[ni], acc[4 + mi][ni], 0, 0, 0);
    }

    // epilogue: C/D layout col=lane&15, row=(lane>>4)*4+reg (m89-verified)
    #pragma unroll
    for (int ni = 0; ni < 4; ++ni) {
        const int col = bn + wn + ni * 16 + l15;
        const float bv = bias[col];
        #pragma unroll
        for (int mi = 0; mi < 8; ++mi) {
            const int row0 = bm + wm + mi * 16 + lh * 4;
            const f32x4 v = acc[mi][ni];
            #pragma unroll
            for (int r = 0; r < 4; ++r)
                C[(size_t)(row0 + r) * N + col] = v[r] + bv;
        }
    }
#undef STAGE_A
#undef STAGE_B
}

extern "C" void kernel_launch(void* const* d_in, const int* in_sizes, int n_in,
                              void* d_out, int out_size, void* d_ws, size_t ws_size,
                              hipStream_t stream) {
    const float* x    = (const float*)d_in[0];
    const float* c0   = (const float*)d_in[1];
    const float* c1   = (const float*)d_in[2];
    const float* c2   = (const float*)d_in[3];
    const float* c3   = (const float*)d_in[4];
    const float* bias = (const float*)d_in[5];
    float* out = (float*)d_out;

    __bf16* xb = (__bf16*)d_ws;                    // 4096*1024 bf16 = 8.39 MB
    __bf16* wt = xb + (size_t)4096 * 1024;         // 4096*1024 bf16 = 8.39 MB

    prep<<<3072, 256, 0, stream>>>(x, xb, c0, c1, c2, c3, wt);
    tt_gemm<<<256, 512, 0, stream>>>(xb, wt, bias, out);
}